// Round 3
// baseline (278.242 us; speedup 1.0000x reference)
//
#include <hip/hip_runtime.h>
#include <math.h>
#include <float.h>

// B=64, C=2, H=W=512. 128 (b,c) maps of 512*512 fp32.
// Kernel 1 (role-split blocks): even blocks = branchless softmax partial sums
//   (l, sx, sy) over a 1/16 split of one inp map; odd blocks = argmax over the
//   matching split of tgt.
//   ROUND 3: the r2 ping-pong was deleted by the compiler (VGPR_Count=28 < the
//   32 the payload alone needs) -> window collapsed, 101us. Max legal window
//   under the frozen numeric topology (16 f4/thread) is ALL 16 loads upfront:
//   f4 x[16] filled straight-line, __builtin_amdgcn_sched_barrier(0) pins the
//   issue before any consume (compiler cannot sink loads across it), then
//   consume k=0..15 ascending -> compiler emits rolling vmcnt(15..0) waits.
//   __launch_bounds__(256,5): VGPR cap 102 holds 64 payload + ~26 overhead;
//   20 waves/CU * 16 deep = +25% in-flight vs r1's 8x32. PLAIN loads (not
//   nontemporal): r2 measured FETCH=134MB of 268MB read -> L3 serves half;
//   NT loads in r0/r1 forfeited that.
//   Per-thread element order (f4 offset tid+256k, k ascending), fma nesting
//   and all reduction topology bitwise-identical to r0/r1 (absmax 0.0).
// Kernel 2: 1024-thread single block: parallel merge of partials via
//   xor-shuffle groups, wave-0 butterfly for scalar outputs. Unchanged.

namespace {
constexpr int S_SPLIT = 16;                 // splits per (b,c) map
constexpr int PAIRS   = 128;                // B*C
constexpr int HW      = 512 * 512;          // 262144
constexpr int CHUNK4  = HW / 4 / S_SPLIT;   // float4s per split = 4096
constexpr int UNITS   = PAIRS * S_SPLIT;    // 2048 (pair,split) units

typedef float f4 __attribute__((ext_vector_type(4)));

struct SmP { float l, sx, sy, pad; };        // 16 B softmax partial
struct AmP { float tv; int ti; };            // 8 B argmax partial
} // namespace

__global__ __launch_bounds__(256, 5) void dsnt_partial(
        const float* __restrict__ inp,
        const float* __restrict__ tgt,
        SmP* __restrict__ smp,
        AmP* __restrict__ amp) {
    const int blk   = blockIdx.x;
    const int kind  = blk & 1;               // 0 = softmax(inp), 1 = argmax(tgt)
    const int unit  = blk >> 1;
    const int pair  = unit >> 4;             // / S_SPLIT
    const int split = unit & (S_SPLIT - 1);
    const int tid   = threadIdx.x;
    const int lane  = tid & 63;
    const int wid   = tid >> 6;
    const int base4 = split * CHUNK4;        // float4 index base within the map
    const float inv = 1.0f / 512.0f;

    __shared__ float sh0[4], sh1[4], sh2[4];
    __shared__ int   sh3[4];

    if (kind == 0) {
        // ---- softmax partial sums over inp split ----
        const f4* p = reinterpret_cast<const f4*>(inp + (size_t)pair * HW) + base4 + tid;
        // element k (f4 offset tid + 256*k): row = split*32 + (tid>>7) + 2k;
        // w coordinate loop-invariant per thread.
        const int w0 = (tid * 4) & 511;
        const float fx0 = (float)(w0 + 1) * inv;
        const float fx1 = (float)(w0 + 2) * inv;
        const float fx2 = (float)(w0 + 3) * inv;
        const float fx3 = (float)(w0 + 4) * inv;
        const int rowbase0 = split * 32 + (tid >> 7);

        // issue ALL 16 dwordx4 loads before any consume
        f4 x[16];
        #pragma unroll
        for (int k = 0; k < 16; ++k)
            x[k] = p[256 * k];
        __builtin_amdgcn_sched_barrier(0);   // loads may not sink past here

        float l = 0.f, sx = 0.f, sy = 0.f;
        #pragma unroll
        for (int k = 0; k < 16; ++k) {       // consume in issue order ->
            const f4 v = x[k];               // rolling vmcnt(15..0) waits
            const float fy = (float)(rowbase0 + 2 * k + 1) * inv;
            const float e0 = __expf(v.x);
            const float e1 = __expf(v.y);
            const float e2 = __expf(v.z);
            const float e3 = __expf(v.w);
            const float es = (e0 + e1) + (e2 + e3);
            l += es;
            sy = fmaf(es, fy, sy);
            sx = fmaf(e0, fx0, fmaf(e1, fx1, fmaf(e2, fx2, fmaf(e3, fx3, sx))));
        }

        #pragma unroll
        for (int off = 32; off > 0; off >>= 1) {
            l  += __shfl_down(l,  off);
            sx += __shfl_down(sx, off);
            sy += __shfl_down(sy, off);
        }
        if (lane == 0) { sh0[wid] = l; sh1[wid] = sx; sh2[wid] = sy; }
        __syncthreads();
        if (tid == 0) {
            float L = 0.f, SX = 0.f, SY = 0.f;
            #pragma unroll
            for (int w = 0; w < 4; ++w) { L += sh0[w]; SX += sh1[w]; SY += sh2[w]; }
            SmP pt; pt.l = L; pt.sx = SX; pt.sy = SY; pt.pad = 0.f;
            smp[unit] = pt;
        }
    } else {
        // ---- argmax over tgt split ----
        const f4* p = reinterpret_cast<const f4*>(tgt + (size_t)pair * HW) + base4 + tid;

        f4 t[16];
        #pragma unroll
        for (int k = 0; k < 16; ++k)
            t[k] = p[256 * k];
        __builtin_amdgcn_sched_barrier(0);

        float tv = -1.0f;                    // target is uniform[0,1) => always beaten
        int   ti = 0;
        #pragma unroll
        for (int k = 0; k < 16; ++k) {
            const f4 v = t[k];
            const int idx = (base4 + tid + 256 * k) * 4;
            bool g;
            g = v.x > tv; tv = g ? v.x : tv; ti = g ? idx     : ti;
            g = v.y > tv; tv = g ? v.y : tv; ti = g ? idx + 1 : ti;
            g = v.z > tv; tv = g ? v.z : tv; ti = g ? idx + 2 : ti;
            g = v.w > tv; tv = g ? v.w : tv; ti = g ? idx + 3 : ti;
        }

        #pragma unroll
        for (int off = 32; off > 0; off >>= 1) {
            const float ov = __shfl_down(tv, off);
            const int   oi = __shfl_down(ti, off);
            if (ov > tv || (ov == tv && oi < ti)) { tv = ov; ti = oi; }
        }
        if (lane == 0) { sh0[wid] = tv; sh3[wid] = ti; }
        __syncthreads();
        if (tid == 0) {
            float TV = -1.0f; int TI = 0x7fffffff;
            #pragma unroll
            for (int w = 0; w < 4; ++w)
                if (sh0[w] > TV || (sh0[w] == TV && sh3[w] < TI)) { TV = sh0[w]; TI = sh3[w]; }
            AmP pt; pt.tv = TV; pt.ti = TI;
            amp[unit] = pt;
        }
    }
}

__global__ __launch_bounds__(1024) void dsnt_final(
        const SmP* __restrict__ smp,
        const AmP* __restrict__ amp,
        float* __restrict__ out, int out_size) {
    __shared__ float pxp[PAIRS], pyp[PAIRS], txp[PAIRS], typ[PAIRS];
    __shared__ float edl[PAIRS], axl[PAIRS], ayl[PAIRS];
    const int tid = threadIdx.x;             // 0..1023; 2 partials/thread

    // merge my 2 partials
    const SmP a  = smp[2 * tid];
    const SmP b  = smp[2 * tid + 1];
    const AmP a2 = amp[2 * tid];
    const AmP b2 = amp[2 * tid + 1];
    float L = a.l + b.l, SX = a.sx + b.sx, SY = a.sy + b.sy;
    float tv = a2.tv; int ti = a2.ti;
    if (b2.tv > tv || (b2.tv == tv && b2.ti < ti)) { tv = b2.tv; ti = b2.ti; }

    // xor-butterfly across the 8-lane group (one pair per group)
    #pragma unroll
    for (int off = 1; off < 8; off <<= 1) {
        L  += __shfl_xor(L,  off);
        SX += __shfl_xor(SX, off);
        SY += __shfl_xor(SY, off);
        const float ov = __shfl_xor(tv, off);
        const int   oi = __shfl_xor(ti, off);
        if (ov > tv || (ov == tv && oi < ti)) { tv = ov; ti = oi; }
    }

    if ((tid & 7) == 0) {
        const int p = tid >> 3;                        // pair index 0..127
        const float px = SX / L * 512.0f;              // pred_xp (pixels)
        const float py = SY / L * 512.0f;              // pred_yp
        const float tx = (float)((ti & 511) + 1);      // true_xp exact
        const float ty = (float)((ti >> 9) + 1);       // true_yp exact
        const float xd = tx - px, yd = ty - py;
        pxp[p] = px; pyp[p] = py; txp[p] = tx; typ[p] = ty;
        edl[p] = sqrtf(xd * xd + yd * yd);
        axl[p] = fabsf(xd);
        ayl[p] = fabsf(yd);
    }
    __syncthreads();

    if (tid < 64) {                                    // wave 0: one lane per batch
        const int bb = tid;
        const float e0 = edl[2 * bb], e1 = edl[2 * bb + 1];
        out[4 + bb] = e0 + e1;                         // tot_list
        const float vpx = pxp[2 * bb] - pxp[2 * bb + 1], vpy = pyp[2 * bb] - pyp[2 * bb + 1];
        const float vtx = txp[2 * bb] - txp[2 * bb + 1], vty = typ[2 * bb] - typ[2 * bb + 1];
        const float pd = sqrtf(vpx * vpx + vpy * vpy);
        const float td = sqrtf(vtx * vtx + vty * vty);
        const float diam = fabsf(pd - td);
        out[68 + bb] = diam;                           // diam_list

        float si = e0, ss = e1, sd = diam;
        float sxs = axl[2 * bb] + axl[2 * bb + 1];
        float sys = ayl[2 * bb] + ayl[2 * bb + 1];
        #pragma unroll
        for (int off = 32; off > 0; off >>= 1) {
            si  += __shfl_xor(si,  off);
            ss  += __shfl_xor(ss,  off);
            sd  += __shfl_xor(sd,  off);
            sxs += __shfl_xor(sxs, off);
            sys += __shfl_xor(sys, off);
        }
        if (tid == 0) {
            out[0] = si;            // s_i
            out[1] = ss;            // s_s
            out[2] = si + ss;       // s_i + s_s
            out[3] = sd;            // s_diam
            out[132] = sxs;         // s_x
            out[133] = sys;         // s_y
            if (out_size >= 135) out[134] = 64.0f;  // B
        }
    }
}

extern "C" void kernel_launch(void* const* d_in, const int* in_sizes, int n_in,
                              void* d_out, int out_size, void* d_ws, size_t ws_size,
                              hipStream_t stream) {
    const float* inp = (const float*)d_in[0];
    const float* tgt = (const float*)d_in[1];
    float* out = (float*)d_out;
    SmP* smp = (SmP*)d_ws;                                  // 2048 * 16 B = 32 KB
    AmP* amp = (AmP*)((char*)d_ws + UNITS * sizeof(SmP));   // 2048 *  8 B = 16 KB

    dsnt_partial<<<UNITS * 2, 256, 0, stream>>>(inp, tgt, smp, amp);
    dsnt_final<<<1, 1024, 0, stream>>>(smp, amp, out, out_size);
}

// Round 4
// 275.047 us; speedup vs baseline: 1.0116x; 1.0116x over previous
//
#include <hip/hip_runtime.h>
#include <math.h>
#include <float.h>

// B=64, C=2, H=W=512. 128 (b,c) maps of 512*512 fp32.
// Kernel 1 (role-split blocks): even blocks = branchless softmax partial sums
//   (l, sx, sy) over a 1/16 split of one inp map; odd blocks = argmax over the
//   matching split of tgt.
//   ROUND 4: r2/r3 proved the HIP compiler collapses any source-level load
//   window (r3: VGPR_Count=40 < the 64 a 16-deep f4 window needs, even with
//   sched_barrier). Fix: 16 separate asm volatile global_load_dwordx4 with
//   distinct "=v" f4 outputs (uniform per-k base in saddr SGPR pair, voffset
//   = tid*16). Volatile ordering + distinct outputs make the 16-deep window
//   impossible to collapse. Compiler doesn't track vmcnt for asm loads, so an
//   explicit s_waitcnt vmcnt(0) + sched_barrier(0) fences all consumes
//   (rule: VALU can be hoisted past asm waitcnt without the sched_barrier).
//   __launch_bounds__(256,5): VGPR cap ~102 = 64 payload + ~20 overhead;
//   20 waves/CU * 16 deep * 16 B = 5 KB/CU in flight, >=2.5x r2/r3 real.
//   Plain loads (not NT): FETCH=134MB of 268MB shows L3 serves half at ~1/3
//   latency. Consume order k=0..15 ascending, fma nesting and reduction
//   topology bitwise-identical to r0-r3 (absmax stays 0.0).
// Kernel 2: 1024-thread single block: parallel merge of partials via
//   xor-shuffle groups, wave-0 butterfly for scalar outputs. Unchanged.

namespace {
constexpr int S_SPLIT = 16;                 // splits per (b,c) map
constexpr int PAIRS   = 128;                // B*C
constexpr int HW      = 512 * 512;          // 262144
constexpr int CHUNK4  = HW / 4 / S_SPLIT;   // float4s per split = 4096
constexpr int UNITS   = PAIRS * S_SPLIT;    // 2048 (pair,split) units

typedef float f4 __attribute__((ext_vector_type(4)));

struct SmP { float l, sx, sy, pad; };        // 16 B softmax partial
struct AmP { float tv; int ti; };            // 8 B argmax partial
} // namespace

// one guaranteed-in-flight dwordx4 load: dst <- mem[sbase_k + tid*16]
#define GLOAD(dst, sbase_k, voff) \
    asm volatile("global_load_dwordx4 %0, %1, %2" \
                 : "=v"(dst) : "v"(voff), "s"(sbase_k) : "memory")

__global__ __launch_bounds__(256, 5) void dsnt_partial(
        const float* __restrict__ inp,
        const float* __restrict__ tgt,
        SmP* __restrict__ smp,
        AmP* __restrict__ amp) {
    const int blk   = blockIdx.x;
    const int kind  = blk & 1;               // 0 = softmax(inp), 1 = argmax(tgt)
    const int unit  = blk >> 1;
    const int pair  = unit >> 4;             // / S_SPLIT
    const int split = unit & (S_SPLIT - 1);
    const int tid   = threadIdx.x;
    const int lane  = tid & 63;
    const int wid   = tid >> 6;
    const int base4 = split * CHUNK4;        // float4 index base within the map
    const float inv = 1.0f / 512.0f;
    const unsigned voff = (unsigned)tid * 16u;   // per-thread byte offset

    __shared__ float sh0[4], sh1[4], sh2[4];
    __shared__ int   sh3[4];

    if (kind == 0) {
        // ---- softmax partial sums over inp split ----
        // element k (f4 offset tid + 256*k): row = split*32 + (tid>>7) + 2k;
        // w coordinate loop-invariant per thread.
        const float* sbase = inp + (size_t)pair * HW + (size_t)base4 * 4;
        const int w0 = (tid * 4) & 511;
        const float fx0 = (float)(w0 + 1) * inv;
        const float fx1 = (float)(w0 + 2) * inv;
        const float fx2 = (float)(w0 + 3) * inv;
        const float fx3 = (float)(w0 + 4) * inv;
        const int rowbase0 = split * 32 + (tid >> 7);

        // 16 guaranteed-in-flight loads (k slice stride = 1024 floats = 4 KB)
        f4 x0, x1, x2, x3, x4, x5, x6, x7, x8, x9, x10, x11, x12, x13, x14, x15;
        GLOAD(x0,  sbase,          voff);  GLOAD(x1,  sbase + 1024,  voff);
        GLOAD(x2,  sbase + 2048,  voff);   GLOAD(x3,  sbase + 3072,  voff);
        GLOAD(x4,  sbase + 4096,  voff);   GLOAD(x5,  sbase + 5120,  voff);
        GLOAD(x6,  sbase + 6144,  voff);   GLOAD(x7,  sbase + 7168,  voff);
        GLOAD(x8,  sbase + 8192,  voff);   GLOAD(x9,  sbase + 9216,  voff);
        GLOAD(x10, sbase + 10240, voff);   GLOAD(x11, sbase + 11264, voff);
        GLOAD(x12, sbase + 12288, voff);   GLOAD(x13, sbase + 13312, voff);
        GLOAD(x14, sbase + 14336, voff);   GLOAD(x15, sbase + 15360, voff);
        asm volatile("s_waitcnt vmcnt(0)" ::: "memory");
        __builtin_amdgcn_sched_barrier(0);   // no consume may cross the wait

        float l = 0.f, sx = 0.f, sy = 0.f;
        auto acc = [&](f4 v, int k) {
            const float fy = (float)(rowbase0 + 2 * k + 1) * inv;
            const float e0 = __expf(v.x);
            const float e1 = __expf(v.y);
            const float e2 = __expf(v.z);
            const float e3 = __expf(v.w);
            const float es = (e0 + e1) + (e2 + e3);
            l += es;
            sy = fmaf(es, fy, sy);
            sx = fmaf(e0, fx0, fmaf(e1, fx1, fmaf(e2, fx2, fmaf(e3, fx3, sx))));
        };
        acc(x0, 0);   acc(x1, 1);   acc(x2, 2);   acc(x3, 3);
        acc(x4, 4);   acc(x5, 5);   acc(x6, 6);   acc(x7, 7);
        acc(x8, 8);   acc(x9, 9);   acc(x10, 10); acc(x11, 11);
        acc(x12, 12); acc(x13, 13); acc(x14, 14); acc(x15, 15);

        #pragma unroll
        for (int off = 32; off > 0; off >>= 1) {
            l  += __shfl_down(l,  off);
            sx += __shfl_down(sx, off);
            sy += __shfl_down(sy, off);
        }
        if (lane == 0) { sh0[wid] = l; sh1[wid] = sx; sh2[wid] = sy; }
        __syncthreads();
        if (tid == 0) {
            float L = 0.f, SX = 0.f, SY = 0.f;
            #pragma unroll
            for (int w = 0; w < 4; ++w) { L += sh0[w]; SX += sh1[w]; SY += sh2[w]; }
            SmP pt; pt.l = L; pt.sx = SX; pt.sy = SY; pt.pad = 0.f;
            smp[unit] = pt;
        }
    } else {
        // ---- argmax over tgt split ----
        const float* tbase = tgt + (size_t)pair * HW + (size_t)base4 * 4;

        f4 t0, t1, t2, t3, t4, t5, t6, t7, t8, t9, t10, t11, t12, t13, t14, t15;
        GLOAD(t0,  tbase,          voff);  GLOAD(t1,  tbase + 1024,  voff);
        GLOAD(t2,  tbase + 2048,  voff);   GLOAD(t3,  tbase + 3072,  voff);
        GLOAD(t4,  tbase + 4096,  voff);   GLOAD(t5,  tbase + 5120,  voff);
        GLOAD(t6,  tbase + 6144,  voff);   GLOAD(t7,  tbase + 7168,  voff);
        GLOAD(t8,  tbase + 8192,  voff);   GLOAD(t9,  tbase + 9216,  voff);
        GLOAD(t10, tbase + 10240, voff);   GLOAD(t11, tbase + 11264, voff);
        GLOAD(t12, tbase + 12288, voff);   GLOAD(t13, tbase + 13312, voff);
        GLOAD(t14, tbase + 14336, voff);   GLOAD(t15, tbase + 15360, voff);
        asm volatile("s_waitcnt vmcnt(0)" ::: "memory");
        __builtin_amdgcn_sched_barrier(0);

        float tv = -1.0f;                    // target is uniform[0,1) => always beaten
        int   ti = 0;
        auto am = [&](f4 v, int k) {
            const int idx = (base4 + tid + 256 * k) * 4;
            bool g;
            g = v.x > tv; tv = g ? v.x : tv; ti = g ? idx     : ti;
            g = v.y > tv; tv = g ? v.y : tv; ti = g ? idx + 1 : ti;
            g = v.z > tv; tv = g ? v.z : tv; ti = g ? idx + 2 : ti;
            g = v.w > tv; tv = g ? v.w : tv; ti = g ? idx + 3 : ti;
        };
        am(t0, 0);   am(t1, 1);   am(t2, 2);   am(t3, 3);
        am(t4, 4);   am(t5, 5);   am(t6, 6);   am(t7, 7);
        am(t8, 8);   am(t9, 9);   am(t10, 10); am(t11, 11);
        am(t12, 12); am(t13, 13); am(t14, 14); am(t15, 15);

        #pragma unroll
        for (int off = 32; off > 0; off >>= 1) {
            const float ov = __shfl_down(tv, off);
            const int   oi = __shfl_down(ti, off);
            if (ov > tv || (ov == tv && oi < ti)) { tv = ov; ti = oi; }
        }
        if (lane == 0) { sh0[wid] = tv; sh3[wid] = ti; }
        __syncthreads();
        if (tid == 0) {
            float TV = -1.0f; int TI = 0x7fffffff;
            #pragma unroll
            for (int w = 0; w < 4; ++w)
                if (sh0[w] > TV || (sh0[w] == TV && sh3[w] < TI)) { TV = sh0[w]; TI = sh3[w]; }
            AmP pt; pt.tv = TV; pt.ti = TI;
            amp[unit] = pt;
        }
    }
}

__global__ __launch_bounds__(1024) void dsnt_final(
        const SmP* __restrict__ smp,
        const AmP* __restrict__ amp,
        float* __restrict__ out, int out_size) {
    __shared__ float pxp[PAIRS], pyp[PAIRS], txp[PAIRS], typ[PAIRS];
    __shared__ float edl[PAIRS], axl[PAIRS], ayl[PAIRS];
    const int tid = threadIdx.x;             // 0..1023; 2 partials/thread

    // merge my 2 partials
    const SmP a  = smp[2 * tid];
    const SmP b  = smp[2 * tid + 1];
    const AmP a2 = amp[2 * tid];
    const AmP b2 = amp[2 * tid + 1];
    float L = a.l + b.l, SX = a.sx + b.sx, SY = a.sy + b.sy;
    float tv = a2.tv; int ti = a2.ti;
    if (b2.tv > tv || (b2.tv == tv && b2.ti < ti)) { tv = b2.tv; ti = b2.ti; }

    // xor-butterfly across the 8-lane group (one pair per group)
    #pragma unroll
    for (int off = 1; off < 8; off <<= 1) {
        L  += __shfl_xor(L,  off);
        SX += __shfl_xor(SX, off);
        SY += __shfl_xor(SY, off);
        const float ov = __shfl_xor(tv, off);
        const int   oi = __shfl_xor(ti, off);
        if (ov > tv || (ov == tv && oi < ti)) { tv = ov; ti = oi; }
    }

    if ((tid & 7) == 0) {
        const int p = tid >> 3;                        // pair index 0..127
        const float px = SX / L * 512.0f;              // pred_xp (pixels)
        const float py = SY / L * 512.0f;              // pred_yp
        const float tx = (float)((ti & 511) + 1);      // true_xp exact
        const float ty = (float)((ti >> 9) + 1);       // true_yp exact
        const float xd = tx - px, yd = ty - py;
        pxp[p] = px; pyp[p] = py; txp[p] = tx; typ[p] = ty;
        edl[p] = sqrtf(xd * xd + yd * yd);
        axl[p] = fabsf(xd);
        ayl[p] = fabsf(yd);
    }
    __syncthreads();

    if (tid < 64) {                                    // wave 0: one lane per batch
        const int bb = tid;
        const float e0 = edl[2 * bb], e1 = edl[2 * bb + 1];
        out[4 + bb] = e0 + e1;                         // tot_list
        const float vpx = pxp[2 * bb] - pxp[2 * bb + 1], vpy = pyp[2 * bb] - pyp[2 * bb + 1];
        const float vtx = txp[2 * bb] - txp[2 * bb + 1], vty = typ[2 * bb] - typ[2 * bb + 1];
        const float pd = sqrtf(vpx * vpx + vpy * vpy);
        const float td = sqrtf(vtx * vtx + vty * vty);
        const float diam = fabsf(pd - td);
        out[68 + bb] = diam;                           // diam_list

        float si = e0, ss = e1, sd = diam;
        float sxs = axl[2 * bb] + axl[2 * bb + 1];
        float sys = ayl[2 * bb] + ayl[2 * bb + 1];
        #pragma unroll
        for (int off = 32; off > 0; off >>= 1) {
            si  += __shfl_xor(si,  off);
            ss  += __shfl_xor(ss,  off);
            sd  += __shfl_xor(sd,  off);
            sxs += __shfl_xor(sxs, off);
            sys += __shfl_xor(sys, off);
        }
        if (tid == 0) {
            out[0] = si;            // s_i
            out[1] = ss;            // s_s
            out[2] = si + ss;       // s_i + s_s
            out[3] = sd;            // s_diam
            out[132] = sxs;         // s_x
            out[133] = sys;         // s_y
            if (out_size >= 135) out[134] = 64.0f;  // B
        }
    }
}

extern "C" void kernel_launch(void* const* d_in, const int* in_sizes, int n_in,
                              void* d_out, int out_size, void* d_ws, size_t ws_size,
                              hipStream_t stream) {
    const float* inp = (const float*)d_in[0];
    const float* tgt = (const float*)d_in[1];
    float* out = (float*)d_out;
    SmP* smp = (SmP*)d_ws;                                  // 2048 * 16 B = 32 KB
    AmP* amp = (AmP*)((char*)d_ws + UNITS * sizeof(SmP));   // 2048 *  8 B = 16 KB

    dsnt_partial<<<UNITS * 2, 256, 0, stream>>>(inp, tgt, smp, amp);
    dsnt_final<<<1, 1024, 0, stream>>>(smp, amp, out, out_size);
}